// Round 4
// baseline (87.192 us; speedup 1.0000x reference)
//
#include <hip/hip_runtime.h>

namespace {
constexpr int Hh = 16;
constexpr int Ll = 1024;
constexpr int Dd = 64;
constexpr int Cc = 64;                   // chunk length
constexpr int NCHUNK = Ll / Cc;          // 16
constexpr float PI_HALF = 1.5707963267948966f;
constexpr float EPSV = 1e-6f;
constexpr int S1 = 72;                   // phase-1 stride (shorts)
constexpr int SA = 200;                  // Aq stride
constexpr int SB = 136;                  // Bk stride
constexpr int SV = 200;                  // Bv stride
}

typedef __attribute__((ext_vector_type(8))) short short8;
typedef __attribute__((ext_vector_type(4))) float floatx4;

__device__ __forceinline__ unsigned short f2bf(float x) {
    unsigned int u = __float_as_uint(x);
    unsigned int r = u + 0x7fffu + ((u >> 16) & 1u);
    return (unsigned short)(r >> 16);
}

// XOR swizzle on j's block-of-8 keyed by the row's block-of-8: keeps MFMA
// fragment reads b128 while spreading the strided transpose writes across
// banks (was ~16-way conflicted unswizzled).
__device__ __forceinline__ int sw1(int row, int j) {
    return (j & 7) | ((((j >> 3) ^ (row >> 3)) & 7) << 3);
}

// One block per (h, chunk c). Phase 1 recomputes the exclusive prefix state
// S[f][d] (+ ksum[f] via a ones-column) over chunks cp < c with MFMA,
// fp32 accumulators. Phase 2 = GEMM1 (scores + denominator) and
// GEMM2 ([scores | qf] x [V ; S]) exactly as validated in round 3.
__global__ __launch_bounds__(256)
void cf_fused(const float* __restrict__ qin, const float* __restrict__ kin,
              const float* __restrict__ vin, float* __restrict__ out) {
    const int c = blockIdx.x, h = blockIdx.y;
    const int tid = threadIdx.x;
    __shared__ unsigned short Ak[128 * S1];   // phase1 A: kf^T [f][j] (swizzled j)
    __shared__ unsigned short Bv1[80 * S1];   // phase1 B: [V|1]^T [n][j] (swizzled j)
    __shared__ unsigned short Aq[64 * SA];    // [l][0..63 scores | 64..191 qf]
    __shared__ unsigned short Bk[80 * SB];    // [n=j][k=f]; row 64 = ksum; 65..79 = 0
    __shared__ unsigned short Bv[64 * SV];    // [n=d][0..63 V^T | 64..191 S]

    const int wave = tid >> 6, lane = tid & 63;
    const int lrow = lane & 15, quad = lane >> 4;

    const size_t hbase = (size_t)h * Ll * Dd;
    const size_t gbase = hbase + (size_t)c * Cc * Dd;

    // ---- issue global loads: own chunk q,k,v + first prefix chunk k,v ----
    const float4* q4 = (const float4*)(qin + gbase);
    const float4* k4 = (const float4*)(kin + gbase);
    const float4* v4 = (const float4*)(vin + gbase);
    float4 oq[4], ok[4], ov[4], pk[4], pv[4];
    #pragma unroll
    for (int i = 0; i < 4; ++i) {
        oq[i] = q4[i * 256 + tid];
        ok[i] = k4[i * 256 + tid];
        ov[i] = v4[i * 256 + tid];
    }
    if (c > 0) {
        const float4* kp = (const float4*)(kin + hbase);
        const float4* vp = (const float4*)(vin + hbase);
        #pragma unroll
        for (int i = 0; i < 4; ++i) {
            pk[i] = kp[i * 256 + tid];
            pv[i] = vp[i * 256 + tid];
        }
    }

    // ---- stage own chunk into phase-2 LDS (not touched by phase 1) ----
    #pragma unroll
    for (int i = 0; i < 4; ++i) {
        int e4 = i * 256 + tid;
        int j = e4 >> 4, d4 = (e4 & 15) * 4;
        float th = PI_HALF * (float)(c * Cc + j + 1) * (1.0f / (float)Ll);
        float sj, cj;
        __sincosf(th, &sj, &cj);
        float q0 = fmaxf(oq[i].x, 0.f), q1 = fmaxf(oq[i].y, 0.f);
        float q2 = fmaxf(oq[i].z, 0.f), q3 = fmaxf(oq[i].w, 0.f);
        *(ushort4*)&Aq[j * SA + 64 + d4] =
            make_ushort4(f2bf(q0 * sj), f2bf(q1 * sj), f2bf(q2 * sj), f2bf(q3 * sj));
        *(ushort4*)&Aq[j * SA + 128 + d4] =
            make_ushort4(f2bf(q0 * cj), f2bf(q1 * cj), f2bf(q2 * cj), f2bf(q3 * cj));
        float k0 = fmaxf(ok[i].x, 0.f), k1 = fmaxf(ok[i].y, 0.f);
        float k2 = fmaxf(ok[i].z, 0.f), k3 = fmaxf(ok[i].w, 0.f);
        *(ushort4*)&Bk[j * SB + d4] =
            make_ushort4(f2bf(k0 * sj), f2bf(k1 * sj), f2bf(k2 * sj), f2bf(k3 * sj));
        *(ushort4*)&Bk[j * SB + 64 + d4] =
            make_ushort4(f2bf(k0 * cj), f2bf(k1 * cj), f2bf(k2 * cj), f2bf(k3 * cj));
        Bv[(d4 + 0) * SV + j] = f2bf(ov[i].x);
        Bv[(d4 + 1) * SV + j] = f2bf(ov[i].y);
        Bv[(d4 + 2) * SV + j] = f2bf(ov[i].z);
        Bv[(d4 + 3) * SV + j] = f2bf(ov[i].w);
    }
    // zero Bk rows 65..79 (15*136 shorts = 1020 u32)
    #pragma unroll
    for (int i = 0; i < 4; ++i) {
        int z = i * 256 + tid;
        if (z < (15 * SB) / 2) ((unsigned int*)Bk)[(65 * SB) / 2 + z] = 0u;
    }
    // Bv1 row 64 = ones (key=0 -> unswizzled is consistent), rows 65..79 = 0
    if (tid < 64) Bv1[64 * S1 + tid] = 0x3F80;
    if (tid >= 64 && tid < S1) Bv1[64 * S1 + tid] = 0;
    #pragma unroll
    for (int i = 0; i < 3; ++i) {
        int z = i * 256 + tid;
        if (z < (15 * S1) / 2) ((unsigned int*)Bv1)[(65 * S1) / 2 + z] = 0u;
    }

    // ---- phase 1: exclusive prefix state, fp32 accumulators ----
    floatx4 acc[2][5];
    #pragma unroll
    for (int t = 0; t < 2; ++t)
        #pragma unroll
        for (int nt = 0; nt < 5; ++nt)
            acc[t][nt] = (floatx4){0.f, 0.f, 0.f, 0.f};

    for (int cp = 0; cp < c; ++cp) {
        #pragma unroll
        for (int i = 0; i < 4; ++i) {
            int e4 = i * 256 + tid;
            int j = e4 >> 4, d4 = (e4 & 15) * 4;
            float th = PI_HALF * (float)(cp * Cc + j + 1) * (1.0f / (float)Ll);
            float sj, cj;
            __sincosf(th, &sj, &cj);
            float r0 = fmaxf(pk[i].x, 0.f), r1 = fmaxf(pk[i].y, 0.f);
            float r2 = fmaxf(pk[i].z, 0.f), r3 = fmaxf(pk[i].w, 0.f);
            int col = sw1(d4, j);    // same key for d4..d4+3 and 64+d4..64+d4+3
            Ak[(d4 + 0) * S1 + col] = f2bf(r0 * sj);
            Ak[(d4 + 1) * S1 + col] = f2bf(r1 * sj);
            Ak[(d4 + 2) * S1 + col] = f2bf(r2 * sj);
            Ak[(d4 + 3) * S1 + col] = f2bf(r3 * sj);
            Ak[(64 + d4 + 0) * S1 + col] = f2bf(r0 * cj);
            Ak[(64 + d4 + 1) * S1 + col] = f2bf(r1 * cj);
            Ak[(64 + d4 + 2) * S1 + col] = f2bf(r2 * cj);
            Ak[(64 + d4 + 3) * S1 + col] = f2bf(r3 * cj);
            Bv1[(d4 + 0) * S1 + col] = f2bf(pv[i].x);
            Bv1[(d4 + 1) * S1 + col] = f2bf(pv[i].y);
            Bv1[(d4 + 2) * S1 + col] = f2bf(pv[i].z);
            Bv1[(d4 + 3) * S1 + col] = f2bf(pv[i].w);
        }
        __syncthreads();
        if (cp + 1 < c) {   // prefetch next chunk (overlaps MFMA below)
            const float4* kp = (const float4*)(kin + hbase + (size_t)(cp + 1) * Cc * Dd);
            const float4* vp = (const float4*)(vin + hbase + (size_t)(cp + 1) * Cc * Dd);
            #pragma unroll
            for (int i = 0; i < 4; ++i) {
                pk[i] = kp[i * 256 + tid];
                pv[i] = vp[i * 256 + tid];
            }
        }
        #pragma unroll
        for (int t = 0; t < 2; ++t) {
            int fr = (wave * 2 + t) * 16 + lrow;
            int keyA = (fr >> 3) & 7;
            short8 a0 = *(const short8*)&Ak[fr * S1 + ((quad ^ keyA) << 3)];
            short8 a1 = *(const short8*)&Ak[fr * S1 + (((4 + quad) ^ keyA) << 3)];
            #pragma unroll
            for (int nt = 0; nt < 5; ++nt) {
                int nr = nt * 16 + lrow;
                int keyB = (nr >> 3) & 7;
                short8 b0 = *(const short8*)&Bv1[nr * S1 + ((quad ^ keyB) << 3)];
                short8 b1 = *(const short8*)&Bv1[nr * S1 + (((4 + quad) ^ keyB) << 3)];
                acc[t][nt] = __builtin_amdgcn_mfma_f32_16x16x32_bf16(a0, b0, acc[t][nt], 0, 0, 0);
                acc[t][nt] = __builtin_amdgcn_mfma_f32_16x16x32_bf16(a1, b1, acc[t][nt], 0, 0, 0);
            }
        }
        __syncthreads();
    }

    // ---- handoff: S -> Bv cols 64.., ksum -> Bk row 64 ----
    #pragma unroll
    for (int t = 0; t < 2; ++t) {
        int fb = wave * 32 + t * 16 + quad * 4;
        #pragma unroll
        for (int nt = 0; nt < 4; ++nt) {
            int d = nt * 16 + lrow;
            *(ushort4*)&Bv[d * SV + 64 + fb] =
                make_ushort4(f2bf(acc[t][nt][0]), f2bf(acc[t][nt][1]),
                             f2bf(acc[t][nt][2]), f2bf(acc[t][nt][3]));
        }
        if (lrow == 0)
            *(ushort4*)&Bk[64 * SB + fb] =
                make_ushort4(f2bf(acc[t][4][0]), f2bf(acc[t][4][1]),
                             f2bf(acc[t][4][2]), f2bf(acc[t][4][3]));
    }
    __syncthreads();

    // ---- GEMM1: scores + denominator ----
    const int l0 = wave * 16;
    const int arow = (l0 + lrow) * SA;
    short8 a1f[4];
    #pragma unroll
    for (int ks = 0; ks < 4; ++ks)
        a1f[ks] = *(const short8*)&Aq[arow + 64 + ks * 32 + quad * 8];
    floatx4 rs = {0.f, 0.f, 0.f, 0.f};
    #pragma unroll
    for (int nt = 0; nt < 5; ++nt) {
        floatx4 s = {0.f, 0.f, 0.f, 0.f};
        #pragma unroll
        for (int ks = 0; ks < 4; ++ks) {
            short8 bf = *(const short8*)&Bk[(nt * 16 + lrow) * SB + ks * 32 + quad * 8];
            s = __builtin_amdgcn_mfma_f32_16x16x32_bf16(a1f[ks], bf, s, 0, 0, 0);
        }
        if (nt < 4) {
            int j = nt * 16 + lrow;
            #pragma unroll
            for (int r = 0; r < 4; ++r) {
                int l = l0 + quad * 4 + r;
                float m = (j <= l) ? s[r] : 0.f;
                s[r] = m;
                Aq[l * SA + j] = f2bf(m);    // masked score -> A-layout for GEMM2
            }
        }
        rs += s;    // nt==4: col 64 = qf.ksum; cols 65..79 exact zeros
    }
    #pragma unroll
    for (int m = 1; m <= 8; m <<= 1) {
        rs[0] += __shfl_xor(rs[0], m);
        rs[1] += __shfl_xor(rs[1], m);
        rs[2] += __shfl_xor(rs[2], m);
        rs[3] += __shfl_xor(rs[3], m);
    }
    float inv[4];
    #pragma unroll
    for (int r = 0; r < 4; ++r) inv[r] = 1.0f / fmaxf(rs[r], EPSV);

    __syncthreads();

    // ---- GEMM2: O = [scores | qf] * [V ; S] ----
    short8 s0 = *(const short8*)&Aq[arow + quad * 8];
    short8 s1 = *(const short8*)&Aq[arow + 32 + quad * 8];
    #pragma unroll
    for (int nt = 0; nt < 4; ++nt) {
        const int brow = (nt * 16 + lrow) * SV;
        floatx4 a2 = {0.f, 0.f, 0.f, 0.f};
        a2 = __builtin_amdgcn_mfma_f32_16x16x32_bf16(
                 s0, *(const short8*)&Bv[brow + quad * 8], a2, 0, 0, 0);
        a2 = __builtin_amdgcn_mfma_f32_16x16x32_bf16(
                 s1, *(const short8*)&Bv[brow + 32 + quad * 8], a2, 0, 0, 0);
        #pragma unroll
        for (int ks = 2; ks < 6; ++ks) {
            short8 bf = *(const short8*)&Bv[brow + ks * 32 + quad * 8];
            a2 = __builtin_amdgcn_mfma_f32_16x16x32_bf16(a1f[ks - 2], bf, a2, 0, 0, 0);
        }
        #pragma unroll
        for (int r = 0; r < 4; ++r) {
            int l = l0 + quad * 4 + r;
            out[gbase + (size_t)l * Dd + nt * 16 + lrow] = a2[r] * inv[r];
        }
    }
}

extern "C" void kernel_launch(void* const* d_in, const int* in_sizes, int n_in,
                              void* d_out, int out_size, void* d_ws, size_t ws_size,
                              hipStream_t stream) {
    const float* q = (const float*)d_in[0];
    const float* k = (const float*)d_in[1];
    const float* v = (const float*)d_in[2];
    float* out = (float*)d_out;
    (void)d_ws; (void)ws_size;    // no workspace needed
    cf_fused<<<dim3(NCHUNK, Hh), 256, 0, stream>>>(q, k, v, out);
}